// Round 11
// baseline (27.090 us; speedup 1.0000x reference)
//
#include <hip/hip_runtime.h>

// Binary-tree circuit — rank-1 factorization, 3 kernels, zero in-kernel
// cross-block sync.  R11 change vs R10: the L2 prefetch in node A is
// PER-XCD-COMPLETE — slice id (bid>>3)&7 means the 8 prefetch blocks that
// land on each XCD (round-robin bid%8 -> XCD) together cover ALL of
// concat(w2..w7) (~1MB), so nodes B and C read XCD-local L2 (~135 GB/s/CU)
// instead of L3 (~55 GB/s/CU).  R10's global slicing left each XCD with only
// ~128KB of the 1MB -> kc streamed L3 (~4-5us instead of ~1.8us).
//
// Math (C=1): every node is h_l[f,b,:] = beta[b] * v_l[f,:].
//   v_{l+1}[o] = w_l[o] @ (v_l[idx_l[2o]] * v_l[idx_l[2o+1]])   (weights only)
//   beta[b]    = prod_{d<256} x[b,d];   out[b,k] = beta[b] * v8[k]
// Exact fp32 reassociation; reference underflows to exact 0 (absmax=0.0,
// R5-R10).
//
// Node A (256 blocks):
//   bid 0-63:   fused level-0 pair + level-1 -> h2g[bid][64]   (R8-proven)
//   bid 64-191: beta, 16 rows each -> betag[2048]              (R6-proven)
//   bid 192+:   per-XCD prefetch of concat(w2..w7), slice (bid>>3)&7
// Node B (16 blocks): levels 2-3 for subtree g -> v4g[g][64]   (R8-proven)
// Node C (256 blocks): redundant fold levels 4-7 from XCD-L2 (R6-proven)
//   + out rows 8*bid..8*bid+7 = beta * v8.

#define NTH 256

struct Params {
  const float* x;     const int* scope;  const float* w_in;
  const int* idx0; const float* w0;  const int* idx1; const float* w1;
  const int* idx2; const float* w2;  const int* idx3; const float* w3;
  const int* idx4; const float* w4;  const int* idx5; const float* w5;
  const int* idx6; const float* w6;  const int* idx7; const float* w7;
  float* h2g;    // ws: [64][64]
  float* v4g;    // ws: [16][64]
  float* betag;  // ws: [2048]
  float* out;  int B;
};

__device__ inline void sinkf4(float4 v) {
  asm volatile("" :: "v"(v.x), "v"(v.y), "v"(v.z), "v"(v.w));
}
__device__ inline float dotp(float4 w, float4 a, float4 b, float acc) {
  acc = fmaf(a.x * b.x, w.x, acc);
  acc = fmaf(a.y * b.y, w.y, acc);
  acc = fmaf(a.z * b.z, w.z, acc);
  acc = fmaf(a.w * b.w, w.w, acc);
  return acc;
}

// ---------------- Node A ----------------------------------------------------
__global__ __launch_bounds__(NTH) void ka_kernel(Params P) {
  const int t = threadIdx.x, bid = blockIdx.x;
  __shared__ float v3[2][64];

  if (bid < 64) {
    // fused level-0 pair + level-1 -> h2g[bid]   (R8-proven body)
    const int o = bid;
    const int ia = P.idx1[2 * o], ib = P.idx1[2 * o + 1];
    {
      const int half = t >> 7, tt = t & 127;    // half 0 -> h1[ia], 1 -> h1[ib]
      const int f = half ? ib : ia;
      const int la = P.idx0[2 * f], lb = P.idx0[2 * f + 1];
      const int oo = tt >> 1, q = tt & 1;       // 2 threads/output, 32 k each
      const float* wr = P.w0   + (size_t)f  * 4096 + oo * 64 + q * 32;
      const float* ar = P.w_in + (size_t)la * 64 + q * 32;
      const float* br = P.w_in + (size_t)lb * 64 + q * 32;
      float acc = 0.f;
      #pragma unroll
      for (int e = 0; e < 8; ++e)
        acc = dotp(*(const float4*)(wr + 4 * e), *(const float4*)(ar + 4 * e),
                   *(const float4*)(br + 4 * e), acc);
      acc += __shfl_xor(acc, 1);
      if (q == 0) v3[half][oo] = acc;
    }
    __syncthreads();
    {
      const int oo = t >> 2, q = t & 3;         // 4 threads/output, 16 k each
      const float* wr = P.w1 + (size_t)o * 4096 + oo * 64 + q * 16;
      float acc = 0.f;
      #pragma unroll
      for (int e = 0; e < 4; ++e)
        acc = dotp(*(const float4*)(wr + 4 * e),
                   *(const float4*)&v3[0][q * 16 + 4 * e],
                   *(const float4*)&v3[1][q * 16 + 4 * e], acc);
      acc += __shfl_xor(acc, 1);
      acc += __shfl_xor(acc, 2);
      if (q == 0) P.h2g[o * 64 + oo] = acc;
    }
  } else if (bid < 192) {
    // beta rows: 16 per block (R6-proven)
    const int r = (bid - 64) * 16 + (t >> 4);
    const int seg = t & 15;
    const float4* xp = (const float4*)(P.x + (size_t)r * 256 + seg * 16);
    float4 u0 = xp[0], u1 = xp[1], u2 = xp[2], u3 = xp[3];
    float pr = ((u0.x * u0.y) * (u0.z * u0.w)) * ((u1.x * u1.y) * (u1.z * u1.w))
             * ((u2.x * u2.y) * (u2.z * u2.w)) * ((u3.x * u3.y) * (u3.z * u3.w));
    pr *= __shfl_xor(pr, 1);
    pr *= __shfl_xor(pr, 2);
    pr *= __shfl_xor(pr, 4);
    pr *= __shfl_xor(pr, 8);
    if (seg == 0) P.betag[r] = pr;
  } else {
    // per-XCD-complete prefetch of concat(w2,w3,w4,w5,w6,w7) = 258048 floats.
    // slice = (bid>>3)&7: blocks 192..199 (one per XCD under bid%8 round-
    // robin) all pull slice 0, 200..207 slice 1, ... -> every XCD's 8 blocks
    // cover all 8 slices (~126KB each, 1MB total per XCD L2).
    const int s = (bid >> 3) & 7;
    const int base4 = s * 8064;               // float4 units (8064*4=32256 fl)
    for (int i4 = t; i4 < 8064; i4 += NTH) {
      const int fi = (base4 + i4) * 4;
      const float* p;
      if      (fi < 131072) p = P.w2 + fi;
      else if (fi < 196608) p = P.w3 + (fi - 131072);
      else if (fi < 229376) p = P.w4 + (fi - 196608);
      else if (fi < 245760) p = P.w5 + (fi - 229376);
      else if (fi < 253952) p = P.w6 + (fi - 245760);
      else                  p = P.w7 + (fi - 253952);
      sinkf4(*(const float4*)p);
    }
  }
}

// ---------------- Node B: levels 2-3, 16 blocks -----------------------------
__global__ __launch_bounds__(NTH) void kb_kernel(Params P) {
  const int t = threadIdx.x, g = blockIdx.x;
  __shared__ float h2s[4][64];
  __shared__ float v3[2][64];

  const int a0 = P.idx3[2 * g], a1 = P.idx3[2 * g + 1];
  const int n0 = P.idx2[2 * a0], n1 = P.idx2[2 * a0 + 1];
  const int n2 = P.idx2[2 * a1], n3 = P.idx2[2 * a1 + 1];
  {
    const int r = t >> 6, c = t & 63;
    const int which = (r == 0) ? n0 : (r == 1) ? n1 : (r == 2) ? n2 : n3;
    h2s[r][c] = P.h2g[which * 64 + c];
  }
  __syncthreads();
  {
    const int opq = t >> 7, oo = (t >> 1) & 63, h = t & 1;
    const float* wr = P.w2 + (size_t)(opq ? a1 : a0) * 4096 + oo * 64 + h * 32;
    const float* ar = &h2s[2 * opq + 0][h * 32];
    const float* br = &h2s[2 * opq + 1][h * 32];
    float acc = 0.f;
    #pragma unroll
    for (int e = 0; e < 8; ++e)
      acc = dotp(*(const float4*)(wr + 4 * e), *(const float4*)(ar + 4 * e),
                 *(const float4*)(br + 4 * e), acc);
    acc += __shfl_xor(acc, 1);
    if (h == 0) v3[opq][oo] = acc;
  }
  __syncthreads();
  {
    const int oo = t >> 2, q = t & 3;
    const float* wr = P.w3 + (size_t)g * 4096 + oo * 64 + q * 16;
    float acc = 0.f;
    #pragma unroll
    for (int e = 0; e < 4; ++e)
      acc = dotp(*(const float4*)(wr + 4 * e),
                 *(const float4*)&v3[0][q * 16 + 4 * e],
                 *(const float4*)&v3[1][q * 16 + 4 * e], acc);
    acc += __shfl_xor(acc, 1);
    acc += __shfl_xor(acc, 2);
    if (q == 0) P.v4g[g * 64 + oo] = acc;
  }
}

// ---------------- Node C: redundant fold levels 4-7 + output ----------------
__global__ __launch_bounds__(NTH) void kc_kernel(Params P) {
  const int t = threadIdx.x, bid = blockIdx.x;
  __shared__ float VA[16][64];
  __shared__ float VB[8][64];
  __shared__ float v8[64];
  __shared__ float beta_s[8];

  if (t < 8) beta_s[t] = P.betag[bid * 8 + t];
  #pragma unroll
  for (int rr = 0; rr < 4; ++rr) {
    const int idx = rr * 256 + t;
    VA[rr * 4 + (t >> 6)][idx & 63] = P.v4g[idx];
  }
  __syncthreads();

  const float* wl[4] = {P.w4, P.w5, P.w6, P.w7};
  const int*   il[4] = {P.idx4, P.idx5, P.idx6, P.idx7};
  const int G = t >> 6, lane = t & 63;
  #pragma unroll
  for (int lev = 0; lev < 4; ++lev) {
    const int nops = 8 >> lev;
    for (int op = G; op < nops; op += 4) {
      const int i0 = il[lev][2 * op], i1 = il[lev][2 * op + 1];
      const float* a = (lev & 1) ? VB[i0] : VA[i0];
      const float* b = (lev & 1) ? VB[i1] : VA[i1];
      const float* wp = wl[lev] + (size_t)op * 4096 + lane * 64;
      float acc = 0.f;
      #pragma unroll
      for (int qq = 0; qq < 16; ++qq)
        acc = dotp(*(const float4*)(wp + 4 * qq), *(const float4*)(a + 4 * qq),
                   *(const float4*)(b + 4 * qq), acc);
      float* dst = (lev == 3) ? v8 : ((lev & 1) ? VA[op] : VB[op]);
      dst[lane] = acc;
    }
    __syncthreads();
  }

  {
    const int row = t >> 5, c0 = (t & 31) * 2;
    const float be = beta_s[row];
    float2 v = *(const float2*)&v8[c0];
    *(float2*)(P.out + (size_t)(bid * 8 + row) * 64 + c0) =
        make_float2(be * v.x, be * v.y);
  }
}

extern "C" void kernel_launch(void* const* d_in, const int* in_sizes, int n_in,
                              void* d_out, int out_size, void* d_ws, size_t ws_size,
                              hipStream_t stream) {
  Params P;
  P.x     = (const float*)d_in[0];
  P.scope = (const int*)d_in[1];
  P.w_in  = (const float*)d_in[2];
  P.idx0 = (const int*)d_in[3];  P.w0 = (const float*)d_in[4];
  P.idx1 = (const int*)d_in[5];  P.w1 = (const float*)d_in[6];
  P.idx2 = (const int*)d_in[7];  P.w2 = (const float*)d_in[8];
  P.idx3 = (const int*)d_in[9];  P.w3 = (const float*)d_in[10];
  P.idx4 = (const int*)d_in[11]; P.w4 = (const float*)d_in[12];
  P.idx5 = (const int*)d_in[13]; P.w5 = (const float*)d_in[14];
  P.idx6 = (const int*)d_in[15]; P.w6 = (const float*)d_in[16];
  P.idx7 = (const int*)d_in[17]; P.w7 = (const float*)d_in[18];
  P.B    = in_sizes[0] / 256;              // 2048
  float* ws = (float*)d_ws;
  P.h2g   = ws;                            // [64][64]
  P.v4g   = ws + 64 * 64;                  // [16][64]
  P.betag = ws + 64 * 64 + 16 * 64;        // [2048]
  P.out   = (float*)d_out;

  ka_kernel<<<256, NTH, 0, stream>>>(P);
  kb_kernel<<<16,  NTH, 0, stream>>>(P);
  kc_kernel<<<256, NTH, 0, stream>>>(P);
}

// Round 12
// 23.437 us; speedup vs baseline: 1.1559x; 1.1559x over previous
//
#include <hip/hip_runtime.h>

// Binary-tree circuit — rank-1 factorization, 3 kernels, zero in-kernel
// cross-block sync, and NO block ever streams more than ~48KB of cold HBM
// (per-CU cold-HBM streaming is ~24 GB/s -> 240KB/block = 10us, the hidden
// cost in R6/R9).  [R12 = R10 verbatim: best-measured clean structure;
// R11's per-XCD prefetch variant measured worse (27.1 vs 23.8, noise ±3us),
// confirming a fixed ~20-23us harness/launch floor dominates dur_us.]
//
// Math (C=1): every node is h_l[f,b,:] = beta[b] * v_l[f,:].
//   v_{l+1}[o] = w_l[o] @ (v_l[idx_l[2o]] * v_l[idx_l[2o+1]])   (weights only)
//   beta[b]    = prod_{d<256} x[b,d];   out[b,k] = beta[b] * v8[k]
// Exact fp32 reassociation; reference underflows to exact 0 (absmax=0.0,
// R5-R11).
//
// Node A (256 blocks):
//   bid 0-63:   fused level-0 pair + level-1 -> h2g[bid][64]   (R8-proven)
//   bid 64-191: beta, 16 rows each -> betag[2048]              (R6-proven)
//   bid 192+:   sink-prefetch 16KB slice of w2..w7 (1MB total) -> L3/L2 warm
// Node B (16 blocks): levels 2-3 for subtree g -> v4g[g][64]   (R8-proven,
//   plain loads of h2g; kernel boundary publishes).
// Node C (256 blocks): redundant fold levels 4-7 from warm cache (R6-proven)
//   + out rows 8*bid..8*bid+7 = beta * v8.

#define NTH 256

struct Params {
  const float* x;     const int* scope;  const float* w_in;
  const int* idx0; const float* w0;  const int* idx1; const float* w1;
  const int* idx2; const float* w2;  const int* idx3; const float* w3;
  const int* idx4; const float* w4;  const int* idx5; const float* w5;
  const int* idx6; const float* w6;  const int* idx7; const float* w7;
  float* h2g;    // ws: [64][64]
  float* v4g;    // ws: [16][64]
  float* betag;  // ws: [2048]
  float* out;  int B;
};

__device__ inline void sinkf4(float4 v) {
  asm volatile("" :: "v"(v.x), "v"(v.y), "v"(v.z), "v"(v.w));
}
__device__ inline float dotp(float4 w, float4 a, float4 b, float acc) {
  acc = fmaf(a.x * b.x, w.x, acc);
  acc = fmaf(a.y * b.y, w.y, acc);
  acc = fmaf(a.z * b.z, w.z, acc);
  acc = fmaf(a.w * b.w, w.w, acc);
  return acc;
}

// ---------------- Node A ----------------------------------------------------
__global__ __launch_bounds__(NTH) void ka_kernel(Params P) {
  const int t = threadIdx.x, bid = blockIdx.x;
  __shared__ float v3[2][64];

  if (bid < 64) {
    // fused level-0 pair + level-1 -> h2g[bid]   (R8-proven body)
    const int o = bid;
    const int ia = P.idx1[2 * o], ib = P.idx1[2 * o + 1];
    {
      const int half = t >> 7, tt = t & 127;    // half 0 -> h1[ia], 1 -> h1[ib]
      const int f = half ? ib : ia;
      const int la = P.idx0[2 * f], lb = P.idx0[2 * f + 1];
      const int oo = tt >> 1, q = tt & 1;       // 2 threads/output, 32 k each
      const float* wr = P.w0   + (size_t)f  * 4096 + oo * 64 + q * 32;
      const float* ar = P.w_in + (size_t)la * 64 + q * 32;
      const float* br = P.w_in + (size_t)lb * 64 + q * 32;
      float acc = 0.f;
      #pragma unroll
      for (int e = 0; e < 8; ++e)
        acc = dotp(*(const float4*)(wr + 4 * e), *(const float4*)(ar + 4 * e),
                   *(const float4*)(br + 4 * e), acc);
      acc += __shfl_xor(acc, 1);
      if (q == 0) v3[half][oo] = acc;
    }
    __syncthreads();
    {
      const int oo = t >> 2, q = t & 3;         // 4 threads/output, 16 k each
      const float* wr = P.w1 + (size_t)o * 4096 + oo * 64 + q * 16;
      float acc = 0.f;
      #pragma unroll
      for (int e = 0; e < 4; ++e)
        acc = dotp(*(const float4*)(wr + 4 * e),
                   *(const float4*)&v3[0][q * 16 + 4 * e],
                   *(const float4*)&v3[1][q * 16 + 4 * e], acc);
      acc += __shfl_xor(acc, 1);
      acc += __shfl_xor(acc, 2);
      if (q == 0) P.h2g[o * 64 + oo] = acc;
    }
  } else if (bid < 192) {
    // beta rows: 16 per block (R6-proven)
    const int r = (bid - 64) * 16 + (t >> 4);
    const int seg = t & 15;
    const float4* xp = (const float4*)(P.x + (size_t)r * 256 + seg * 16);
    float4 u0 = xp[0], u1 = xp[1], u2 = xp[2], u3 = xp[3];
    float pr = ((u0.x * u0.y) * (u0.z * u0.w)) * ((u1.x * u1.y) * (u1.z * u1.w))
             * ((u2.x * u2.y) * (u2.z * u2.w)) * ((u3.x * u3.y) * (u3.z * u3.w));
    pr *= __shfl_xor(pr, 1);
    pr *= __shfl_xor(pr, 2);
    pr *= __shfl_xor(pr, 4);
    pr *= __shfl_xor(pr, 8);
    if (seg == 0) P.betag[r] = pr;
  } else {
    // prefetch slice of concat(w2,w3,w4,w5,w6,w7) = 258048 floats over 64 blks
    const int s = bid - 192;                  // 4032 floats (=1008 float4) each
    const int base = s * 4032;
    for (int i = t * 4; i < 4032; i += NTH * 4) {
      const int fi = base + i;
      const float* p;
      if      (fi < 131072) p = P.w2 + fi;
      else if (fi < 196608) p = P.w3 + (fi - 131072);
      else if (fi < 229376) p = P.w4 + (fi - 196608);
      else if (fi < 245760) p = P.w5 + (fi - 229376);
      else if (fi < 253952) p = P.w6 + (fi - 245760);
      else                  p = P.w7 + (fi - 253952);
      sinkf4(*(const float4*)p);
    }
  }
}

// ---------------- Node B: levels 2-3, 16 blocks -----------------------------
__global__ __launch_bounds__(NTH) void kb_kernel(Params P) {
  const int t = threadIdx.x, g = blockIdx.x;
  __shared__ float h2s[4][64];
  __shared__ float v3[2][64];

  const int a0 = P.idx3[2 * g], a1 = P.idx3[2 * g + 1];
  const int n0 = P.idx2[2 * a0], n1 = P.idx2[2 * a0 + 1];
  const int n2 = P.idx2[2 * a1], n3 = P.idx2[2 * a1 + 1];
  {
    const int r = t >> 6, c = t & 63;
    const int which = (r == 0) ? n0 : (r == 1) ? n1 : (r == 2) ? n2 : n3;
    h2s[r][c] = P.h2g[which * 64 + c];
  }
  __syncthreads();
  {
    const int opq = t >> 7, oo = (t >> 1) & 63, h = t & 1;
    const float* wr = P.w2 + (size_t)(opq ? a1 : a0) * 4096 + oo * 64 + h * 32;
    const float* ar = &h2s[2 * opq + 0][h * 32];
    const float* br = &h2s[2 * opq + 1][h * 32];
    float acc = 0.f;
    #pragma unroll
    for (int e = 0; e < 8; ++e)
      acc = dotp(*(const float4*)(wr + 4 * e), *(const float4*)(ar + 4 * e),
                 *(const float4*)(br + 4 * e), acc);
    acc += __shfl_xor(acc, 1);
    if (h == 0) v3[opq][oo] = acc;
  }
  __syncthreads();
  {
    const int oo = t >> 2, q = t & 3;
    const float* wr = P.w3 + (size_t)g * 4096 + oo * 64 + q * 16;
    float acc = 0.f;
    #pragma unroll
    for (int e = 0; e < 4; ++e)
      acc = dotp(*(const float4*)(wr + 4 * e),
                 *(const float4*)&v3[0][q * 16 + 4 * e],
                 *(const float4*)&v3[1][q * 16 + 4 * e], acc);
    acc += __shfl_xor(acc, 1);
    acc += __shfl_xor(acc, 2);
    if (q == 0) P.v4g[g * 64 + oo] = acc;
  }
}

// ---------------- Node C: redundant fold levels 4-7 + output ----------------
__global__ __launch_bounds__(NTH) void kc_kernel(Params P) {
  const int t = threadIdx.x, bid = blockIdx.x;
  __shared__ float VA[16][64];
  __shared__ float VB[8][64];
  __shared__ float v8[64];
  __shared__ float beta_s[8];

  if (t < 8) beta_s[t] = P.betag[bid * 8 + t];
  #pragma unroll
  for (int rr = 0; rr < 4; ++rr) {
    const int idx = rr * 256 + t;
    VA[rr * 4 + (t >> 6)][idx & 63] = P.v4g[idx];
  }
  __syncthreads();

  const float* wl[4] = {P.w4, P.w5, P.w6, P.w7};
  const int*   il[4] = {P.idx4, P.idx5, P.idx6, P.idx7};
  const int G = t >> 6, lane = t & 63;
  #pragma unroll
  for (int lev = 0; lev < 4; ++lev) {
    const int nops = 8 >> lev;
    for (int op = G; op < nops; op += 4) {
      const int i0 = il[lev][2 * op], i1 = il[lev][2 * op + 1];
      const float* a = (lev & 1) ? VB[i0] : VA[i0];
      const float* b = (lev & 1) ? VB[i1] : VA[i1];
      const float* wp = wl[lev] + (size_t)op * 4096 + lane * 64;
      float acc = 0.f;
      #pragma unroll
      for (int qq = 0; qq < 16; ++qq)
        acc = dotp(*(const float4*)(wp + 4 * qq), *(const float4*)(a + 4 * qq),
                   *(const float4*)(b + 4 * qq), acc);
      float* dst = (lev == 3) ? v8 : ((lev & 1) ? VA[op] : VB[op]);
      dst[lane] = acc;
    }
    __syncthreads();
  }

  {
    const int row = t >> 5, c0 = (t & 31) * 2;
    const float be = beta_s[row];
    float2 v = *(const float2*)&v8[c0];
    *(float2*)(P.out + (size_t)(bid * 8 + row) * 64 + c0) =
        make_float2(be * v.x, be * v.y);
  }
}

extern "C" void kernel_launch(void* const* d_in, const int* in_sizes, int n_in,
                              void* d_out, int out_size, void* d_ws, size_t ws_size,
                              hipStream_t stream) {
  Params P;
  P.x     = (const float*)d_in[0];
  P.scope = (const int*)d_in[1];
  P.w_in  = (const float*)d_in[2];
  P.idx0 = (const int*)d_in[3];  P.w0 = (const float*)d_in[4];
  P.idx1 = (const int*)d_in[5];  P.w1 = (const float*)d_in[6];
  P.idx2 = (const int*)d_in[7];  P.w2 = (const float*)d_in[8];
  P.idx3 = (const int*)d_in[9];  P.w3 = (const float*)d_in[10];
  P.idx4 = (const int*)d_in[11]; P.w4 = (const float*)d_in[12];
  P.idx5 = (const int*)d_in[13]; P.w5 = (const float*)d_in[14];
  P.idx6 = (const int*)d_in[15]; P.w6 = (const float*)d_in[16];
  P.idx7 = (const int*)d_in[17]; P.w7 = (const float*)d_in[18];
  P.B    = in_sizes[0] / 256;              // 2048
  float* ws = (float*)d_ws;
  P.h2g   = ws;                            // [64][64]
  P.v4g   = ws + 64 * 64;                  // [16][64]
  P.betag = ws + 64 * 64 + 16 * 64;        // [2048]
  P.out   = (float*)d_out;

  ka_kernel<<<256, NTH, 0, stream>>>(P);
  kb_kernel<<<16,  NTH, 0, stream>>>(P);
  kc_kernel<<<256, NTH, 0, stream>>>(P);
}